// Round 13
// baseline (576.726 us; speedup 1.0000x reference)
//
#include <hip/hip_runtime.h>
#include <hip/hip_fp16.h>

typedef unsigned short u16;
typedef __attribute__((ext_vector_type(8))) short bf16x8;
typedef __attribute__((ext_vector_type(4))) float f32x4;

#define T_SEQ 2048
#define DIM 1024
#define NB 4
#define NCH 16        // 128-row chunks for column-softmax reduce

__device__ __forceinline__ u16 f2bf(float f) {
  union { float f; unsigned u; } c; c.f = f;
  unsigned r = c.u + 0x7fffu + ((c.u >> 16) & 1u);
  return (u16)(r >> 16);
}

__device__ __forceinline__ void gload_lds16(const void* g, void* l) {
  __builtin_amdgcn_global_load_lds((const __attribute__((address_space(1))) void*)g,
                                   (__attribute__((address_space(3))) void*)l, 16, 0, 0);
}

// ========== fused LayerNorm (rows) + weight bf16 convert (one launch) =======
__global__ __launch_bounds__(256) void prep_kernel(
    const float* __restrict__ x, const float* __restrict__ gamma,
    const float* __restrict__ beta, u16* __restrict__ xn,
    const float* __restrict__ wq, const float* __restrict__ wk,
    const float* __restrict__ wv, const float* __restrict__ wo,
    u16* __restrict__ dqk, u16* __restrict__ dv, u16* __restrict__ dw) {
  const int tid = threadIdx.x;
  if (blockIdx.x < NB * T_SEQ) {
    // ---- LayerNorm row ----
    const int row = blockIdx.x;
    const float4 v = *(const float4*)(x + (size_t)row * DIM + tid * 4);
    float s  = v.x + v.y + v.z + v.w;
    float ss = v.x * v.x + v.y * v.y + v.z * v.z + v.w * v.w;
#pragma unroll
    for (int o = 32; o > 0; o >>= 1) { s += __shfl_down(s, o); ss += __shfl_down(ss, o); }
    __shared__ float rs[4], rss[4];
    const int wid = tid >> 6, lane = tid & 63;
    if (lane == 0) { rs[wid] = s; rss[wid] = ss; }
    __syncthreads();
    s  = rs[0] + rs[1] + rs[2] + rs[3];
    ss = rss[0] + rss[1] + rss[2] + rss[3];
    const float mu = s * (1.f / DIM);
    const float var = ss * (1.f / DIM) - mu * mu;
    const float rstd = rsqrtf(var + 1e-5f);
    const float4 g  = *(const float4*)(gamma + tid * 4);
    const float4 be = *(const float4*)(beta + tid * 4);
    ushort4 o;
    o.x = f2bf((v.x - mu) * rstd * g.x + be.x);
    o.y = f2bf((v.y - mu) * rstd * g.y + be.y);
    o.z = f2bf((v.z - mu) * rstd * g.z + be.z);
    o.w = f2bf((v.w - mu) * rstd * g.w + be.w);
    *(ushort4*)(xn + (size_t)row * DIM + tid * 4) = o;
  } else {
    // ---- weight convert ----
    const int bid = blockIdx.x - NB * T_SEQ;
    const int sel = bid >> 10;
    const size_t t = (size_t)(bid & 1023) * 256 + tid;
    const float* w = (sel == 0) ? wq : (sel == 1) ? wk : (sel == 2) ? wv : wo;
    u16* d = (sel == 0) ? dqk : (sel == 1) ? (dqk + 1048576) : (sel == 2) ? dv : dw;
    const float4 v = *(const float4*)(w + t * 4);
    ushort4 u; u.x = f2bf(v.x); u.y = f2bf(v.y); u.z = f2bf(v.z); u.w = f2bf(v.w);
    *(ushort4*)(d + t * 4) = u;
  }
}

// ======= m97-style GEMM: 128x128 tile, BK=64, 4 waves, single 32KB buffer ===
// (proven; used for PV and Wo)
// EPI 2: bf16 + aux residual (batched f32)   3: f32, +bias[col], relu
// MSK 0: none   2 (PV): if tileM >= l[bz], emit y = bf16(x) and skip
template <int EPI, int MSK>
__global__ __launch_bounds__(256, 4) void gemm97(
    const u16* __restrict__ A, const u16* __restrict__ B, void* __restrict__ Cv,
    int K, int lda, int ldb, int ldc,
    long sA, long sB, long sC,
    const float* __restrict__ aux, long sAux,
    const int* __restrict__ lptr) {
  __shared__ __align__(16) u16 As[128 * 64];
  __shared__ __align__(16) u16 Bs[128 * 64];
  const int bz = blockIdx.z;
  const u16* Ab = A + (size_t)bz * sA;
  const u16* Bb = B + (size_t)bz * sB;

  const int nb = gridDim.x * gridDim.y;
  int bid = blockIdx.y * gridDim.x + blockIdx.x;
  bid = (bid & 7) * (nb >> 3) + (bid >> 3);
  const int gx = gridDim.x;
  const int tileN = (bid % gx) * 128;
  const int tileM = (bid / gx) * 128;

  const int t = threadIdx.x;

  if constexpr (MSK == 2) {
    if (tileM >= lptr[bz]) {                  // P rows zero -> y = x
      const float* xb = aux + (size_t)bz * sAux;
      u16* yo = (u16*)Cv + (size_t)bz * sC;
      for (int e = t; e < (128 * 128) / 8; e += 256) {
        const int row = tileM + (e >> 4);
        const int col = tileN + ((e & 15) << 3);
        const float4 v0 = *(const float4*)(xb + (size_t)row * ldc + col);
        const float4 v1 = *(const float4*)(xb + (size_t)row * ldc + col + 4);
        ushort4 o0; o0.x = f2bf(v0.x); o0.y = f2bf(v0.y); o0.z = f2bf(v0.z); o0.w = f2bf(v0.w);
        ushort4 o1; o1.x = f2bf(v1.x); o1.y = f2bf(v1.y); o1.z = f2bf(v1.z); o1.w = f2bf(v1.w);
        *(ushort4*)(yo + (size_t)row * ldc + col) = o0;
        *(ushort4*)(yo + (size_t)row * ldc + col + 4) = o1;
      }
      return;
    }
  }

  const int lane = t & 63;
  const int wid = t >> 6;
  const int wm = wid >> 1, wn = wid & 1;      // 2 x 2 waves

  const int r0s = t >> 3;
  const int sch = ((t & 7) ^ (r0s & 7)) * 8;

  const int frow = lane & 15, kg = lane >> 4, f7 = lane & 7;

  f32x4 acc[4][4] = {};

  for (int k0 = 0; k0 < K; k0 += 64) {
    if (k0) __syncthreads();
#pragma unroll
    for (int i = 0; i < 4; ++i) {
      const int e = i * 256 + t;
      const int row = i * 32 + r0s;
      gload_lds16(Ab + (size_t)(tileM + row) * lda + k0 + sch, &As[e * 8]);
      gload_lds16(Bb + (size_t)(tileN + row) * ldb + k0 + sch, &Bs[e * 8]);
    }
    __syncthreads();
#pragma unroll
    for (int h = 0; h < 2; ++h) {
      const int cs = (((h * 4 + kg) ^ f7)) * 8;
      bf16x8 af[4], bf[4];
#pragma unroll
      for (int i = 0; i < 4; ++i)
        af[i] = *(const bf16x8*)&As[(wm * 64 + i * 16 + frow) * 64 + cs];
#pragma unroll
      for (int j = 0; j < 4; ++j)
        bf[j] = *(const bf16x8*)&Bs[(wn * 64 + j * 16 + frow) * 64 + cs];
#pragma unroll
      for (int i = 0; i < 4; ++i)
#pragma unroll
        for (int j = 0; j < 4; ++j)
          acc[i][j] = __builtin_amdgcn_mfma_f32_16x16x32_bf16(af[i], bf[j], acc[i][j], 0, 0, 0);
    }
  }

  const int r0 = tileM + wm * 64 + (kg << 2);
  const int c0 = tileN + wn * 64 + frow;
#pragma unroll
  for (int i = 0; i < 4; ++i)
#pragma unroll
    for (int j = 0; j < 4; ++j)
#pragma unroll
      for (int r = 0; r < 4; ++r) {
        const int row = r0 + i * 16 + r, col = c0 + j * 16;
        const size_t idx = (size_t)row * ldc + col;
        float v = acc[i][j][r];
        if constexpr (EPI == 2) {
          v += (aux + (size_t)bz * sAux)[idx];
          ((u16*)Cv + (size_t)bz * sC)[idx] = f2bf(v);
        } else {
          v += aux[col];
          ((float*)Cv + (size_t)bz * sC)[idx] = fmaxf(v, 0.f);
        }
      }
}

// ==== dual-role dispatch: QK (wide 128x256) + V^T (97 128x128) interleaved ==
// 1024 blocks, role = bid&1. Both read only xn. 48KB LDS, 3 blocks/CU.
// QK: C[8192,2048] = xn @ wqk^T; dead Q-half tiles (rows >= l) skip -> their
// CU slots immediately refill with V^T blocks.
// Vt: C[1024,8192] = wv @ xn^T.
__global__ __launch_bounds__(256, 3) void gemm_qkvt(
    const u16* __restrict__ xn, const u16* __restrict__ wqk,
    const u16* __restrict__ wv, u16* __restrict__ QK, u16* __restrict__ Vt,
    const int* __restrict__ lptr) {
  __shared__ __align__(16) u16 As[128 * 64];   // 16 KB
  __shared__ __align__(16) u16 Bs[256 * 64];   // 32 KB
  const int t = threadIdx.x;
  const int role = blockIdx.x & 1;
  const int sub = blockIdx.x >> 1;             // 0..511 per role
  const int sw = (sub & 7) * 64 + (sub >> 3);  // XCD swizzle over 512

  const int lane = t & 63;
  const int wid = t >> 6;
  const int wm = wid >> 1, wn = wid & 1;
  const int r0s = t >> 3;
  const int sch = ((t & 7) ^ (r0s & 7)) * 8;
  const int frow = lane & 15, kg = lane >> 4, f7 = lane & 7;

  if (role == 0) {
    // ---------------- wide QK: BM=128 x BN=256, wave tile 64x128 ------------
    const int tileN = (sw & 7) * 256;          // gx = 8
    const int tileM = (sw >> 3) * 128;         // 64 M-tiles
    if (((tileM & (T_SEQ - 1)) >= lptr[tileM >> 11]) && tileN < DIM) return;

    f32x4 acc[4][8] = {};
    for (int k0 = 0; k0 < DIM; k0 += 64) {
      if (k0) __syncthreads();
#pragma unroll
      for (int i = 0; i < 4; ++i) {
        const int row = i * 32 + r0s;
        gload_lds16(xn + (size_t)(tileM + row) * DIM + k0 + sch, &As[(i * 256 + t) * 8]);
      }
#pragma unroll
      for (int i = 0; i < 8; ++i) {
        const int row = i * 32 + r0s;
        gload_lds16(wqk + (size_t)(tileN + row) * DIM + k0 + sch, &Bs[(i * 256 + t) * 8]);
      }
      __syncthreads();
#pragma unroll
      for (int h = 0; h < 2; ++h) {
        const int cs = (((h * 4 + kg) ^ f7)) * 8;
        bf16x8 af[4], bf[8];
#pragma unroll
        for (int i = 0; i < 4; ++i)
          af[i] = *(const bf16x8*)&As[(wm * 64 + i * 16 + frow) * 64 + cs];
#pragma unroll
        for (int j = 0; j < 8; ++j)
          bf[j] = *(const bf16x8*)&Bs[(wn * 128 + j * 16 + frow) * 64 + cs];
#pragma unroll
        for (int i = 0; i < 4; ++i)
#pragma unroll
          for (int j = 0; j < 8; ++j)
            acc[i][j] = __builtin_amdgcn_mfma_f32_16x16x32_bf16(af[i], bf[j], acc[i][j], 0, 0, 0);
      }
    }
    const int r0 = tileM + wm * 64 + (kg << 2);
    const int c0 = tileN + wn * 128 + frow;
#pragma unroll
    for (int i = 0; i < 4; ++i)
#pragma unroll
      for (int j = 0; j < 8; ++j)
#pragma unroll
        for (int r = 0; r < 4; ++r)
          QK[(size_t)(r0 + i * 16 + r) * 2048 + c0 + j * 16] = f2bf(acc[i][j][r]);
  } else {
    // ---------------- 97-style V^T: 128x128 -------------------------------
    const int tileN = (sw & 63) * 128;         // gx = 64
    const int tileM = (sw >> 6) * 128;         // 8 M-tiles
    f32x4 acc[4][4] = {};
    for (int k0 = 0; k0 < DIM; k0 += 64) {
      if (k0) __syncthreads();
#pragma unroll
      for (int i = 0; i < 4; ++i) {
        const int e = i * 256 + t;
        const int row = i * 32 + r0s;
        gload_lds16(wv + (size_t)(tileM + row) * DIM + k0 + sch, &As[e * 8]);
        gload_lds16(xn + (size_t)(tileN + row) * DIM + k0 + sch, &Bs[e * 8]);
      }
      __syncthreads();
#pragma unroll
      for (int h = 0; h < 2; ++h) {
        const int cs = (((h * 4 + kg) ^ f7)) * 8;
        bf16x8 af[4], bf[4];
#pragma unroll
        for (int i = 0; i < 4; ++i)
          af[i] = *(const bf16x8*)&As[(wm * 64 + i * 16 + frow) * 64 + cs];
#pragma unroll
        for (int j = 0; j < 4; ++j)
          bf[j] = *(const bf16x8*)&Bs[(wn * 64 + j * 16 + frow) * 64 + cs];
#pragma unroll
        for (int i = 0; i < 4; ++i)
#pragma unroll
          for (int j = 0; j < 4; ++j)
            acc[i][j] = __builtin_amdgcn_mfma_f32_16x16x32_bf16(af[i], bf[j], acc[i][j], 0, 0, 0);
      }
    }
    const int r0 = tileM + wm * 64 + (kg << 2);
    const int c0 = tileN + wn * 64 + frow;
#pragma unroll
    for (int i = 0; i < 4; ++i)
#pragma unroll
      for (int j = 0; j < 4; ++j)
#pragma unroll
        for (int r = 0; r < 4; ++r)
          Vt[(size_t)(r0 + i * 16 + r) * 8192 + c0 + j * 16] = f2bf(acc[i][j][r]);
  }
}

// ==== wide-wave GEMM: BM=128 x BN=256, wave tile 64x128 (S kernel) =========
// EPI: fp16*scale store + fused per-column masked (max,sumexp) partials.
// MSK: skip tile if tileM >= l[bz].
__global__ __launch_bounds__(256, 3) void gemm_bw_s(
    const u16* __restrict__ A, const u16* __restrict__ B, __half* __restrict__ Cv,
    int K, int lda, int ldb, int ldc,
    long sA, long sB, long sC, float scale,
    const int* __restrict__ lptr, float* __restrict__ mpQ, float* __restrict__ zpQ) {
  __shared__ __align__(16) u16 As[128 * 64];
  __shared__ __align__(16) u16 Bs[256 * 64];
  const int bz = blockIdx.z;
  const u16* Ab = A + (size_t)bz * sA;
  const u16* Bb = B + (size_t)bz * sB;

  const int nb = gridDim.x * gridDim.y;
  int bid = blockIdx.y * gridDim.x + blockIdx.x;
  bid = (bid & 7) * (nb >> 3) + (bid >> 3);
  const int gx = gridDim.x;
  const int tileN = (bid % gx) * 256;
  const int tileM = (bid / gx) * 128;

  const int t = threadIdx.x;
  if (tileM >= lptr[bz]) return;

  const int lane = t & 63;
  const int wid = t >> 6;
  const int wm = wid >> 1, wn = wid & 1;
  const int r0s = t >> 3;
  const int sch = ((t & 7) ^ (r0s & 7)) * 8;
  const int frow = lane & 15, kg = lane >> 4, f7 = lane & 7;

  f32x4 acc[4][8] = {};

  for (int k0 = 0; k0 < K; k0 += 64) {
    if (k0) __syncthreads();
#pragma unroll
    for (int i = 0; i < 4; ++i) {
      const int row = i * 32 + r0s;
      gload_lds16(Ab + (size_t)(tileM + row) * lda + k0 + sch, &As[(i * 256 + t) * 8]);
    }
#pragma unroll
    for (int i = 0; i < 8; ++i) {
      const int row = i * 32 + r0s;
      gload_lds16(Bb + (size_t)(tileN + row) * ldb + k0 + sch, &Bs[(i * 256 + t) * 8]);
    }
    __syncthreads();
#pragma unroll
    for (int h = 0; h < 2; ++h) {
      const int cs = (((h * 4 + kg) ^ f7)) * 8;
      bf16x8 af[4], bf[8];
#pragma unroll
      for (int i = 0; i < 4; ++i)
        af[i] = *(const bf16x8*)&As[(wm * 64 + i * 16 + frow) * 64 + cs];
#pragma unroll
      for (int j = 0; j < 8; ++j)
        bf[j] = *(const bf16x8*)&Bs[(wn * 128 + j * 16 + frow) * 64 + cs];
#pragma unroll
      for (int i = 0; i < 4; ++i)
#pragma unroll
        for (int j = 0; j < 8; ++j)
          acc[i][j] = __builtin_amdgcn_mfma_f32_16x16x32_bf16(af[i], bf[j], acc[i][j], 0, 0, 0);
    }
  }

  const int r0 = tileM + wm * 64 + (kg << 2);
  const int c0 = tileN + wn * 128 + frow;
#pragma unroll
  for (int i = 0; i < 4; ++i)
#pragma unroll
    for (int j = 0; j < 8; ++j)
#pragma unroll
      for (int r = 0; r < 4; ++r) {
        const int row = r0 + i * 16 + r, col = c0 + j * 16;
        (Cv + (size_t)bz * sC)[(size_t)row * ldc + col] = __float2half(acc[i][j][r] * scale);
      }

  // fused per-column (over rows i, masked i<L) max & sumexp partials
  const int L = lptr[bz];
  __shared__ float2 red[2][2][8][16];
  float Ms[8], Zs[8];
#pragma unroll
  for (int j = 0; j < 8; ++j) {
    float mj = -3e38f;
#pragma unroll
    for (int i = 0; i < 4; ++i)
#pragma unroll
      for (int r = 0; r < 4; ++r) {
        const int row = r0 + i * 16 + r;
        if (row < L) mj = fmaxf(mj, acc[i][j][r] * scale);
      }
    mj = fmaxf(mj, __shfl_xor(mj, 16, 64));
    mj = fmaxf(mj, __shfl_xor(mj, 32, 64));
    float zj = 0.f;
#pragma unroll
    for (int i = 0; i < 4; ++i)
#pragma unroll
      for (int r = 0; r < 4; ++r) {
        const int row = r0 + i * 16 + r;
        if (row < L) zj += __expf(acc[i][j][r] * scale - mj);
      }
    zj += __shfl_xor(zj, 16, 64);
    zj += __shfl_xor(zj, 32, 64);
    Ms[j] = mj; Zs[j] = zj;
  }
  if (lane < 16) {
#pragma unroll
    for (int j = 0; j < 8; ++j) red[wm][wn][j][frow] = make_float2(Ms[j], Zs[j]);
  }
  __syncthreads();
  if (wm == 0 && lane < 16) {
#pragma unroll
    for (int j = 0; j < 8; ++j) {
      const float2 a = red[0][wn][j][frow];
      const float2 b = red[1][wn][j][frow];
      const float M = fmaxf(a.x, b.x);
      const float Z = a.y * __expf(a.x - M) + b.y * __expf(b.x - M);
      const int col = tileN + wn * 128 + j * 16 + frow;
      const size_t o = ((size_t)(tileM >> 7) * NB + bz) * T_SEQ + col;
      mpQ[o] = M; zpQ[o] = Z;
    }
  }
}

// ------- combine live chunk partials per column -> m, 1/Z -------------------
__global__ __launch_bounds__(256) void colreduce_comb(const float* __restrict__ mp,
                                                      const float* __restrict__ zp,
                                                      const int* __restrict__ l,
                                                      float* __restrict__ m,
                                                      float* __restrict__ rz) {
  const int b = blockIdx.y;
  const int j = blockIdx.x * 256 + threadIdx.x;
  const int L = l[b];
  float M = -3e38f, Z = 0.f;
  for (int c = 0; c < NCH && (c << 7) < L; ++c) {
    const size_t o = ((size_t)c * NB + b) * T_SEQ + j;
    const float mc = mp[o], zc = zp[o];
    const float nm = fmaxf(M, mc);
    Z = Z * __expf(M - nm) + zc * __expf(mc - nm);
    M = nm;
  }
  m[b * T_SEQ + j] = M;
  rz[b * T_SEQ + j] = 1.f / Z;
}

// ---------------- P = exp(S - m) / Z  (bf16, row-masked) -------------------
__global__ __launch_bounds__(256) void pbuild(const __half* __restrict__ S,
                                              const int* __restrict__ l,
                                              const float* __restrict__ m,
                                              const float* __restrict__ rz,
                                              u16* __restrict__ P) {
  const int b = blockIdx.x >> 11;
  const int i = blockIdx.x & (T_SEQ - 1);
  const int L = l[b];
  if (i >= ((L + 127) & ~127)) return;
  const int j0 = threadIdx.x * 8;
  const size_t off = ((size_t)blockIdx.x << 11) + j0;
  ushort4 o0, o1;
  if (i < L) {
    const __half* sp = S + off;
    const float* mp = m + b * T_SEQ + j0;
    const float* zp = rz + b * T_SEQ + j0;
    u16 tmp[8];
#pragma unroll
    for (int tt = 0; tt < 8; ++tt)
      tmp[tt] = f2bf(__expf(__half2float(sp[tt]) - mp[tt]) * zp[tt]);
    o0 = make_ushort4(tmp[0], tmp[1], tmp[2], tmp[3]);
    o1 = make_ushort4(tmp[4], tmp[5], tmp[6], tmp[7]);
  } else {
    o0 = make_ushort4(0, 0, 0, 0);
    o1 = make_ushort4(0, 0, 0, 0);
  }
  *(ushort4*)(P + off) = o0;
  *(ushort4*)(P + off + 4) = o1;
}

// ---------------------------------------------------------------------------
extern "C" void kernel_launch(void* const* d_in, const int* in_sizes, int n_in,
                              void* d_out, int out_size, void* d_ws, size_t ws_size,
                              hipStream_t stream) {
  (void)in_sizes; (void)n_in; (void)out_size; (void)ws_size;
  const float* x     = (const float*)d_in[0];
  const int*   l     = (const int*)d_in[1];
  const float* Wq    = (const float*)d_in[2];
  const float* Wk    = (const float*)d_in[3];
  const float* Wv    = (const float*)d_in[4];
  const float* Wo    = (const float*)d_in[5];
  const float* bo    = (const float*)d_in[6];
  const float* gamma = (const float*)d_in[7];
  const float* beta  = (const float*)d_in[8];

  char* ws = (char*)d_ws;
  const size_t MiB = 1024 * 1024;
  u16* xn   = (u16*)(ws);             // 16 MiB x_norm; later reused as y
  u16* wqkb = (u16*)(ws + 16 * MiB);  // 4 MiB: Wq rows then Wk rows (concat)
  u16* wvb  = (u16*)(ws + 20 * MiB);  // 2 MiB; later reused for softmax partials
  u16* wob  = (u16*)(ws + 22 * MiB);  // 2 MiB
  u16* QKb  = (u16*)(ws + 24 * MiB);  // 32 MiB: [8192][2048] Q|K; reused as P
  u16* Vt   = (u16*)(ws + 56 * MiB);  // 16 MiB: [1024][8192] V^T (all batches)
  float* mpart = (float*)(ws + 20 * MiB);                // 512 KiB (over dead wvb)
  float* zpart = (float*)(ws + 20 * MiB + 512 * 1024);   // 512 KiB
  float* mb  = (float*)(ws + 72 * MiB);
  float* rzb = (float*)(ws + 72 * MiB + 32 * 1024);
  u16* Pb = QKb;                      // P overwrites dead Q|K
  u16* yb = xn;
  __half* S = (__half*)d_out;         // d_out doubles as the 32 MiB score scratch
  float* outp = (float*)d_out;

  const long TD = (long)T_SEQ * DIM, TT = (long)T_SEQ * T_SEQ;
  const long TQK = (long)T_SEQ * 2048;

  // LayerNorm + weight converts in one launch
  prep_kernel<<<NB * T_SEQ + 4096, 256, 0, stream>>>(
      x, gamma, beta, xn, Wq, Wk, Wv, Wo, wqkb, wvb, wob);

  // Q|K (wide, dead-tile skip) + V^T (97) in one interleaved 1024-block launch
  gemm_qkvt<<<1024, 256, 0, stream>>>(xn, wqkb, wvb, QKb, Vt, l);

  // S[b] = (Q_b @ K_b^T)*scale -> fp16, + fused per-column partial (m,z)
  gemm_bw_s<<<dim3(8, 16, NB), 256, 0, stream>>>(
      QKb, QKb + 1024, S, DIM, 2048, 2048, T_SEQ, TQK, TQK, TT, 0.03125f,
      l, mpart, zpart);
  // combine live chunk partials -> m, 1/Z
  colreduce_comb<<<dim3(T_SEQ / 256, NB), 256, 0, stream>>>(mpart, zpart, l, mb, rzb);
  // P = exp(S-m)*rz (bf16), zero straddle band, skip fully-dead rows
  pbuild<<<NB * T_SEQ, 256, 0, stream>>>(S, l, mb, rzb, Pb);
  // y[b] = x_b + P_b @ Vt_b^T  [2048,1024] bf16  grid 8x16x4 = 512
  gemm97<2, 2><<<dim3(8, 16, NB), 256, 0, stream>>>(
      Pb, Vt, yb, T_SEQ, T_SEQ, 8192, DIM, TT, 2048, TD, x, TD, l);
  // out = relu(y @ Wo^T + bo)  f32   grid 8x64 = 512
  gemm97<3, 0><<<dim3(8, 64, 1), 256, 0, stream>>>(
      yb, wob, outp, DIM, DIM, DIM, DIM, 0, 0, 0, bo, 0, nullptr);
}

// Round 14
// 200.600 us; speedup vs baseline: 2.8750x; 2.8750x over previous
//
#include <hip/hip_runtime.h>
#include <hip/hip_fp16.h>

typedef unsigned short u16;
typedef __attribute__((ext_vector_type(8))) short bf16x8;
typedef __attribute__((ext_vector_type(4))) float f32x4;

#define T_SEQ 2048
#define DIM 1024
#define NB 4
#define NCH 16        // 128-row chunks for column-softmax reduce

__device__ __forceinline__ u16 f2bf(float f) {
  union { float f; unsigned u; } c; c.f = f;
  unsigned r = c.u + 0x7fffu + ((c.u >> 16) & 1u);
  return (u16)(r >> 16);
}

__device__ __forceinline__ void gload_lds16(const void* g, void* l) {
  __builtin_amdgcn_global_load_lds((const __attribute__((address_space(1))) void*)g,
                                   (__attribute__((address_space(3))) void*)l, 16, 0, 0);
}

// ---------------- LayerNorm: x (f32) -> x_norm (bf16) ----------------
__global__ __launch_bounds__(256) void ln_kernel(const float* __restrict__ x,
                                                 const float* __restrict__ gamma,
                                                 const float* __restrict__ beta,
                                                 u16* __restrict__ xn) {
  const int row = blockIdx.x;
  const int tid = threadIdx.x;
  const float4 v = *(const float4*)(x + (size_t)row * DIM + tid * 4);
  float s  = v.x + v.y + v.z + v.w;
  float ss = v.x * v.x + v.y * v.y + v.z * v.z + v.w * v.w;
#pragma unroll
  for (int o = 32; o > 0; o >>= 1) { s += __shfl_down(s, o); ss += __shfl_down(ss, o); }
  __shared__ float rs[4], rss[4];
  const int wid = tid >> 6, lane = tid & 63;
  if (lane == 0) { rs[wid] = s; rss[wid] = ss; }
  __syncthreads();
  s  = rs[0] + rs[1] + rs[2] + rs[3];
  ss = rss[0] + rss[1] + rss[2] + rss[3];
  const float mu = s * (1.f / DIM);
  const float var = ss * (1.f / DIM) - mu * mu;
  const float rstd = rsqrtf(var + 1e-5f);
  const float4 g  = *(const float4*)(gamma + tid * 4);
  const float4 be = *(const float4*)(beta + tid * 4);
  ushort4 o;
  o.x = f2bf((v.x - mu) * rstd * g.x + be.x);
  o.y = f2bf((v.y - mu) * rstd * g.y + be.y);
  o.z = f2bf((v.z - mu) * rstd * g.z + be.z);
  o.w = f2bf((v.w - mu) * rstd * g.w + be.w);
  *(ushort4*)(xn + (size_t)row * DIM + tid * 4) = o;
}

// ---------------- f32 -> bf16 weight convert, all 4 weights in one launch ---
__global__ __launch_bounds__(256) void wcvt4(const float* __restrict__ wq,
                                             const float* __restrict__ wk,
                                             const float* __restrict__ wv,
                                             const float* __restrict__ wo,
                                             u16* __restrict__ dqk,
                                             u16* __restrict__ dv,
                                             u16* __restrict__ dw) {
  const int sel = blockIdx.x >> 10;
  const size_t t = (size_t)(blockIdx.x & 1023) * 256 + threadIdx.x;
  const float* w = (sel == 0) ? wq : (sel == 1) ? wk : (sel == 2) ? wv : wo;
  u16* d = (sel == 0) ? dqk : (sel == 1) ? (dqk + 1048576) : (sel == 2) ? dv : dw;
  const float4 v = *(const float4*)(w + t * 4);
  ushort4 u; u.x = f2bf(v.x); u.y = f2bf(v.y); u.z = f2bf(v.z); u.w = f2bf(v.w);
  *(ushort4*)(d + t * 4) = u;
}

// ======= m97-style GEMM: 128x128 tile, BK=64, 4 waves, single 32KB buffer ===
// (proven round-10 kernel; used for V^T, PV, Wo)
// EPI 0: bf16   2: bf16 + aux residual (batched f32)   3: f32, +bias[col], relu
// MSK 0: none   2 (PV): if tileM >= l[bz], emit y = bf16(x) and skip
template <int EPI, int MSK>
__global__ __launch_bounds__(256, 4) void gemm97(
    const u16* __restrict__ A, const u16* __restrict__ B, void* __restrict__ Cv,
    int K, int lda, int ldb, int ldc,
    long sA, long sB, long sC,
    const float* __restrict__ aux, long sAux,
    const int* __restrict__ lptr) {
  __shared__ __align__(16) u16 As[128 * 64];
  __shared__ __align__(16) u16 Bs[128 * 64];
  const int bz = blockIdx.z;
  const u16* Ab = A + (size_t)bz * sA;
  const u16* Bb = B + (size_t)bz * sB;

  const int nb = gridDim.x * gridDim.y;
  int bid = blockIdx.y * gridDim.x + blockIdx.x;
  bid = (bid & 7) * (nb >> 3) + (bid >> 3);
  const int gx = gridDim.x;
  const int tileN = (bid % gx) * 128;
  const int tileM = (bid / gx) * 128;

  const int t = threadIdx.x;

  if constexpr (MSK == 2) {
    if (tileM >= lptr[bz]) {                  // P rows zero -> y = x
      const float* xb = aux + (size_t)bz * sAux;
      u16* yo = (u16*)Cv + (size_t)bz * sC;
      for (int e = t; e < (128 * 128) / 8; e += 256) {
        const int row = tileM + (e >> 4);
        const int col = tileN + ((e & 15) << 3);
        const float4 v0 = *(const float4*)(xb + (size_t)row * ldc + col);
        const float4 v1 = *(const float4*)(xb + (size_t)row * ldc + col + 4);
        ushort4 o0; o0.x = f2bf(v0.x); o0.y = f2bf(v0.y); o0.z = f2bf(v0.z); o0.w = f2bf(v0.w);
        ushort4 o1; o1.x = f2bf(v1.x); o1.y = f2bf(v1.y); o1.z = f2bf(v1.z); o1.w = f2bf(v1.w);
        *(ushort4*)(yo + (size_t)row * ldc + col) = o0;
        *(ushort4*)(yo + (size_t)row * ldc + col + 4) = o1;
      }
      return;
    }
  }

  const int lane = t & 63;
  const int wid = t >> 6;
  const int wm = wid >> 1, wn = wid & 1;      // 2 x 2 waves

  const int r0s = t >> 3;
  const int sch = ((t & 7) ^ (r0s & 7)) * 8;

  const int frow = lane & 15, kg = lane >> 4, f7 = lane & 7;

  f32x4 acc[4][4] = {};

  for (int k0 = 0; k0 < K; k0 += 64) {
    if (k0) __syncthreads();
#pragma unroll
    for (int i = 0; i < 4; ++i) {
      const int e = i * 256 + t;
      const int row = i * 32 + r0s;
      gload_lds16(Ab + (size_t)(tileM + row) * lda + k0 + sch, &As[e * 8]);
      gload_lds16(Bb + (size_t)(tileN + row) * ldb + k0 + sch, &Bs[e * 8]);
    }
    __syncthreads();
#pragma unroll
    for (int h = 0; h < 2; ++h) {
      const int cs = (((h * 4 + kg) ^ f7)) * 8;
      bf16x8 af[4], bf[4];
#pragma unroll
      for (int i = 0; i < 4; ++i)
        af[i] = *(const bf16x8*)&As[(wm * 64 + i * 16 + frow) * 64 + cs];
#pragma unroll
      for (int j = 0; j < 4; ++j)
        bf[j] = *(const bf16x8*)&Bs[(wn * 64 + j * 16 + frow) * 64 + cs];
#pragma unroll
      for (int i = 0; i < 4; ++i)
#pragma unroll
        for (int j = 0; j < 4; ++j)
          acc[i][j] = __builtin_amdgcn_mfma_f32_16x16x32_bf16(af[i], bf[j], acc[i][j], 0, 0, 0);
    }
  }

  const int r0 = tileM + wm * 64 + (kg << 2);
  const int c0 = tileN + wn * 64 + frow;
#pragma unroll
  for (int i = 0; i < 4; ++i)
#pragma unroll
    for (int j = 0; j < 4; ++j)
#pragma unroll
      for (int r = 0; r < 4; ++r) {
        const int row = r0 + i * 16 + r, col = c0 + j * 16;
        const size_t idx = (size_t)row * ldc + col;
        float v = acc[i][j][r];
        if constexpr (EPI == 0) {
          ((u16*)Cv + (size_t)bz * sC)[idx] = f2bf(v);
        } else if constexpr (EPI == 2) {
          v += (aux + (size_t)bz * sAux)[idx];
          ((u16*)Cv + (size_t)bz * sC)[idx] = f2bf(v);
        } else {
          v += aux[col];
          ((float*)Cv + (size_t)bz * sC)[idx] = fmaxf(v, 0.f);
        }
      }
}

// ==== wide-wave GEMM: BM=128 x BN=256, 4 waves (2x2), wave tile 64x128 ======
// acc[4][8] (128 VGPR), BK=64, single 48KB LDS buffer, 2 blocks/CU.
// 2x FLOP per barrier and 0.75x LDS traffic per FLOP vs the 128^2 kernel.
// EPI 0: bf16   1: fp16*scale + fused per-column masked (max,sumexp) partials
// MSK 1: skip tile if tileM >= l[bz]
// MSK 3 (QK): skip Q-half tiles (tileN < DIM) whose rows are all >= l[batch]
template <int EPI, int MSK>
__global__ __launch_bounds__(256, 2) void gemm_bw(
    const u16* __restrict__ A, const u16* __restrict__ B, void* __restrict__ Cv,
    int K, int lda, int ldb, int ldc,
    long sA, long sB, long sC, float scale,
    const int* __restrict__ lptr, float* __restrict__ mpQ, float* __restrict__ zpQ) {
  __shared__ __align__(16) u16 As[128 * 64];   // 16 KB
  __shared__ __align__(16) u16 Bs[256 * 64];   // 32 KB
  const int bz = blockIdx.z;
  const u16* Ab = A + (size_t)bz * sA;
  const u16* Bb = B + (size_t)bz * sB;

  const int nb = gridDim.x * gridDim.y;
  int bid = blockIdx.y * gridDim.x + blockIdx.x;
  bid = (bid & 7) * (nb >> 3) + (bid >> 3);
  const int gx = gridDim.x;
  const int tileN = (bid % gx) * 256;
  const int tileM = (bid / gx) * 128;

  const int t = threadIdx.x;

  if constexpr (MSK == 1) {
    if (tileM >= lptr[bz]) return;
  }
  if constexpr (MSK == 3) {
    if (((tileM & (T_SEQ - 1)) >= lptr[tileM >> 11]) && tileN < DIM) return;
  }

  const int lane = t & 63;
  const int wid = t >> 6;
  const int wm = wid >> 1, wn = wid & 1;      // 2M x 2N waves

  const int r0s = t >> 3;
  const int sch = ((t & 7) ^ (r0s & 7)) * 8;

  const int frow = lane & 15, kg = lane >> 4, f7 = lane & 7;

  f32x4 acc[4][8] = {};

  for (int k0 = 0; k0 < K; k0 += 64) {
    if (k0) __syncthreads();
#pragma unroll
    for (int i = 0; i < 4; ++i) {
      const int row = i * 32 + r0s;
      gload_lds16(Ab + (size_t)(tileM + row) * lda + k0 + sch, &As[(i * 256 + t) * 8]);
    }
#pragma unroll
    for (int i = 0; i < 8; ++i) {
      const int row = i * 32 + r0s;
      gload_lds16(Bb + (size_t)(tileN + row) * ldb + k0 + sch, &Bs[(i * 256 + t) * 8]);
    }
    __syncthreads();
#pragma unroll
    for (int h = 0; h < 2; ++h) {
      const int cs = (((h * 4 + kg) ^ f7)) * 8;
      bf16x8 af[4], bf[8];
#pragma unroll
      for (int i = 0; i < 4; ++i)
        af[i] = *(const bf16x8*)&As[(wm * 64 + i * 16 + frow) * 64 + cs];
#pragma unroll
      for (int j = 0; j < 8; ++j)
        bf[j] = *(const bf16x8*)&Bs[(wn * 128 + j * 16 + frow) * 64 + cs];
#pragma unroll
      for (int i = 0; i < 4; ++i)
#pragma unroll
        for (int j = 0; j < 8; ++j)
          acc[i][j] = __builtin_amdgcn_mfma_f32_16x16x32_bf16(af[i], bf[j], acc[i][j], 0, 0, 0);
    }
  }

  const int r0 = tileM + wm * 64 + (kg << 2);
  const int c0 = tileN + wn * 128 + frow;
#pragma unroll
  for (int i = 0; i < 4; ++i)
#pragma unroll
    for (int j = 0; j < 8; ++j)
#pragma unroll
      for (int r = 0; r < 4; ++r) {
        const int row = r0 + i * 16 + r, col = c0 + j * 16;
        const size_t idx = (size_t)row * ldc + col;
        const float v = acc[i][j][r];
        if constexpr (EPI == 0) {
          ((u16*)Cv + (size_t)bz * sC)[idx] = f2bf(v);
        } else {
          ((__half*)Cv + (size_t)bz * sC)[idx] = __float2half(v * scale);
        }
      }

  // ---- EPI 1: fused per-column (over rows i, masked i<L) max & sumexp ------
  if constexpr (EPI == 1) {
    const int L = lptr[bz];
    __shared__ float2 red[2][2][8][16];   // [wm][wn][j][frow]
    float Ms[8], Zs[8];
#pragma unroll
    for (int j = 0; j < 8; ++j) {
      float mj = -3e38f;
#pragma unroll
      for (int i = 0; i < 4; ++i)
#pragma unroll
        for (int r = 0; r < 4; ++r) {
          const int row = r0 + i * 16 + r;
          if (row < L) mj = fmaxf(mj, acc[i][j][r] * scale);
        }
      mj = fmaxf(mj, __shfl_xor(mj, 16, 64));
      mj = fmaxf(mj, __shfl_xor(mj, 32, 64));
      float zj = 0.f;
#pragma unroll
      for (int i = 0; i < 4; ++i)
#pragma unroll
        for (int r = 0; r < 4; ++r) {
          const int row = r0 + i * 16 + r;
          if (row < L) zj += __expf(acc[i][j][r] * scale - mj);
        }
      zj += __shfl_xor(zj, 16, 64);
      zj += __shfl_xor(zj, 32, 64);
      Ms[j] = mj; Zs[j] = zj;
    }
    if (lane < 16) {
#pragma unroll
      for (int j = 0; j < 8; ++j) red[wm][wn][j][frow] = make_float2(Ms[j], Zs[j]);
    }
    __syncthreads();
    if (wm == 0 && lane < 16) {
#pragma unroll
      for (int j = 0; j < 8; ++j) {
        const float2 a = red[0][wn][j][frow];
        const float2 b = red[1][wn][j][frow];
        const float M = fmaxf(a.x, b.x);
        const float Z = a.y * __expf(a.x - M) + b.y * __expf(b.x - M);
        const int col = tileN + wn * 128 + j * 16 + frow;
        const size_t o = ((size_t)(tileM >> 7) * NB + bz) * T_SEQ + col;
        mpQ[o] = M; zpQ[o] = Z;
      }
    }
  }
}

// ------- combine live chunk partials per column -> m, 1/Z -------------------
__global__ __launch_bounds__(256) void colreduce_comb(const float* __restrict__ mp,
                                                      const float* __restrict__ zp,
                                                      const int* __restrict__ l,
                                                      float* __restrict__ m,
                                                      float* __restrict__ rz) {
  const int b = blockIdx.y;
  const int j = blockIdx.x * 256 + threadIdx.x;
  const int L = l[b];
  float M = -3e38f, Z = 0.f;
  for (int c = 0; c < NCH && (c << 7) < L; ++c) {
    const size_t o = ((size_t)c * NB + b) * T_SEQ + j;
    const float mc = mp[o], zc = zp[o];
    const float nm = fmaxf(M, mc);
    Z = Z * __expf(M - nm) + zc * __expf(mc - nm);
    M = nm;
  }
  m[b * T_SEQ + j] = M;
  rz[b * T_SEQ + j] = 1.f / Z;
}

// ---------------- P = exp(S - m) / Z  (bf16, row-masked) -------------------
__global__ __launch_bounds__(256) void pbuild(const __half* __restrict__ S,
                                              const int* __restrict__ l,
                                              const float* __restrict__ m,
                                              const float* __restrict__ rz,
                                              u16* __restrict__ P) {
  const int b = blockIdx.x >> 11;
  const int i = blockIdx.x & (T_SEQ - 1);
  const int L = l[b];
  if (i >= ((L + 127) & ~127)) return;
  const int j0 = threadIdx.x * 8;
  const size_t off = ((size_t)blockIdx.x << 11) + j0;
  ushort4 o0, o1;
  if (i < L) {
    const __half* sp = S + off;
    const float* mp = m + b * T_SEQ + j0;
    const float* zp = rz + b * T_SEQ + j0;
    u16 tmp[8];
#pragma unroll
    for (int tt = 0; tt < 8; ++tt)
      tmp[tt] = f2bf(__expf(__half2float(sp[tt]) - mp[tt]) * zp[tt]);
    o0 = make_ushort4(tmp[0], tmp[1], tmp[2], tmp[3]);
    o1 = make_ushort4(tmp[4], tmp[5], tmp[6], tmp[7]);
  } else {
    o0 = make_ushort4(0, 0, 0, 0);
    o1 = make_ushort4(0, 0, 0, 0);
  }
  *(ushort4*)(P + off) = o0;
  *(ushort4*)(P + off + 4) = o1;
}

// ---------------------------------------------------------------------------
extern "C" void kernel_launch(void* const* d_in, const int* in_sizes, int n_in,
                              void* d_out, int out_size, void* d_ws, size_t ws_size,
                              hipStream_t stream) {
  (void)in_sizes; (void)n_in; (void)out_size; (void)ws_size;
  const float* x     = (const float*)d_in[0];
  const int*   l     = (const int*)d_in[1];
  const float* Wq    = (const float*)d_in[2];
  const float* Wk    = (const float*)d_in[3];
  const float* Wv    = (const float*)d_in[4];
  const float* Wo    = (const float*)d_in[5];
  const float* bo    = (const float*)d_in[6];
  const float* gamma = (const float*)d_in[7];
  const float* beta  = (const float*)d_in[8];

  char* ws = (char*)d_ws;
  const size_t MiB = 1024 * 1024;
  u16* xn   = (u16*)(ws);             // 16 MiB x_norm; later reused as y
  u16* wqkb = (u16*)(ws + 16 * MiB);  // 4 MiB: Wq rows then Wk rows (concat)
  u16* wvb  = (u16*)(ws + 20 * MiB);  // 2 MiB; later reused for softmax partials
  u16* wob  = (u16*)(ws + 22 * MiB);  // 2 MiB
  u16* QKb  = (u16*)(ws + 24 * MiB);  // 32 MiB: [8192][2048] Q|K; reused as P
  u16* Vt   = (u16*)(ws + 56 * MiB);  // 16 MiB: [1024][8192] V^T (all batches)
  float* mpart = (float*)(ws + 20 * MiB);                // 512 KiB (over dead wvb)
  float* zpart = (float*)(ws + 20 * MiB + 512 * 1024);   // 512 KiB
  float* mb  = (float*)(ws + 72 * MiB);
  float* rzb = (float*)(ws + 72 * MiB + 32 * 1024);
  u16* Pb = QKb;                      // P overwrites dead Q|K
  u16* yb = xn;
  __half* S = (__half*)d_out;         // d_out doubles as the 32 MiB score scratch
  float* outp = (float*)d_out;

  const long TD = (long)T_SEQ * DIM, TT = (long)T_SEQ * T_SEQ;
  const long TQK = (long)T_SEQ * 2048;

  ln_kernel<<<NB * T_SEQ, 256, 0, stream>>>(x, gamma, beta, xn);
  wcvt4<<<4096, 256, 0, stream>>>(Wq, Wk, Wv, Wo, wqkb, wvb, wob);

  // Q|K = xn @ [Wq;Wk]^T  [8192,2048]  grid 8x64 = 512 (dead Q-tiles skip)
  gemm_bw<0, 3><<<dim3(8, 64, 1), 256, 0, stream>>>(
      xn, wqkb, QKb, DIM, DIM, DIM, 2048, 0, 0, 0, 0.f,
      l, nullptr, nullptr);
  // V^T = Wv_bf @ xn^T   [1024, 8192]   grid 64x8 = 512
  gemm97<0, 0><<<dim3(64, 8, 1), 256, 0, stream>>>(
      wvb, xn, Vt, DIM, DIM, DIM, 8192, 0, 0, 0, nullptr, 0, nullptr);
  // S[b] = (Q_b @ K_b^T)*scale -> fp16, + fused per-column partial (m,z)
  // grid 8x16x4 = 512 (tiles with all rows masked skip; slots refill)
  gemm_bw<1, 1><<<dim3(8, 16, NB), 256, 0, stream>>>(
      QKb, QKb + 1024, S, DIM, 2048, 2048, T_SEQ, TQK, TQK, TT, 0.03125f,
      l, mpart, zpart);
  // combine live chunk partials -> m, 1/Z
  colreduce_comb<<<dim3(T_SEQ / 256, NB), 256, 0, stream>>>(mpart, zpart, l, mb, rzb);
  // P = exp(S-m)*rz (bf16), zero straddle band, skip fully-dead rows
  pbuild<<<NB * T_SEQ, 256, 0, stream>>>(S, l, mb, rzb, Pb);
  // y[b] = x_b + P_b @ Vt_b^T  [2048,1024] bf16  grid 8x16x4 = 512
  gemm97<2, 2><<<dim3(8, 16, NB), 256, 0, stream>>>(
      Pb, Vt, yb, T_SEQ, T_SEQ, 8192, DIM, TT, 2048, TD, x, TD, l);
  // out = relu(y @ Wo^T + bo)  f32   grid 8x64 = 512
  gemm97<3, 0><<<dim3(8, 64, 1), 256, 0, stream>>>(
      yb, wob, outp, DIM, DIM, DIM, DIM, 0, 0, 0, bo, 0, nullptr);
}

// Round 15
// 200.594 us; speedup vs baseline: 2.8751x; 1.0000x over previous
//
#include <hip/hip_runtime.h>
#include <hip/hip_fp16.h>

typedef unsigned short u16;
typedef __attribute__((ext_vector_type(8))) short bf16x8;
typedef __attribute__((ext_vector_type(4))) float f32x4;

#define T_SEQ 2048
#define DIM 1024
#define NB 4
#define NCH 16        // 128-row chunks for column-softmax reduce

__device__ __forceinline__ u16 f2bf(float f) {
  union { float f; unsigned u; } c; c.f = f;
  unsigned r = c.u + 0x7fffu + ((c.u >> 16) & 1u);
  return (u16)(r >> 16);
}

__device__ __forceinline__ void gload_lds16(const void* g, void* l) {
  __builtin_amdgcn_global_load_lds((const __attribute__((address_space(1))) void*)g,
                                   (__attribute__((address_space(3))) void*)l, 16, 0, 0);
}

// ---------------- LayerNorm: x (f32) -> x_norm (bf16) ----------------
__global__ __launch_bounds__(256) void ln_kernel(const float* __restrict__ x,
                                                 const float* __restrict__ gamma,
                                                 const float* __restrict__ beta,
                                                 u16* __restrict__ xn) {
  const int row = blockIdx.x;
  const int tid = threadIdx.x;
  const float4 v = *(const float4*)(x + (size_t)row * DIM + tid * 4);
  float s  = v.x + v.y + v.z + v.w;
  float ss = v.x * v.x + v.y * v.y + v.z * v.z + v.w * v.w;
#pragma unroll
  for (int o = 32; o > 0; o >>= 1) { s += __shfl_down(s, o); ss += __shfl_down(ss, o); }
  __shared__ float rs[4], rss[4];
  const int wid = tid >> 6, lane = tid & 63;
  if (lane == 0) { rs[wid] = s; rss[wid] = ss; }
  __syncthreads();
  s  = rs[0] + rs[1] + rs[2] + rs[3];
  ss = rss[0] + rss[1] + rss[2] + rss[3];
  const float mu = s * (1.f / DIM);
  const float var = ss * (1.f / DIM) - mu * mu;
  const float rstd = rsqrtf(var + 1e-5f);
  const float4 g  = *(const float4*)(gamma + tid * 4);
  const float4 be = *(const float4*)(beta + tid * 4);
  ushort4 o;
  o.x = f2bf((v.x - mu) * rstd * g.x + be.x);
  o.y = f2bf((v.y - mu) * rstd * g.y + be.y);
  o.z = f2bf((v.z - mu) * rstd * g.z + be.z);
  o.w = f2bf((v.w - mu) * rstd * g.w + be.w);
  *(ushort4*)(xn + (size_t)row * DIM + tid * 4) = o;
}

// ---------------- f32 -> bf16 weight convert, all 4 weights in one launch ---
__global__ __launch_bounds__(256) void wcvt4(const float* __restrict__ wq,
                                             const float* __restrict__ wk,
                                             const float* __restrict__ wv,
                                             const float* __restrict__ wo,
                                             u16* __restrict__ dqk,
                                             u16* __restrict__ dv,
                                             u16* __restrict__ dw) {
  const int sel = blockIdx.x >> 10;
  const size_t t = (size_t)(blockIdx.x & 1023) * 256 + threadIdx.x;
  const float* w = (sel == 0) ? wq : (sel == 1) ? wk : (sel == 2) ? wv : wo;
  u16* d = (sel == 0) ? dqk : (sel == 1) ? (dqk + 1048576) : (sel == 2) ? dv : dw;
  const float4 v = *(const float4*)(w + t * 4);
  ushort4 u; u.x = f2bf(v.x); u.y = f2bf(v.y); u.z = f2bf(v.z); u.w = f2bf(v.w);
  *(ushort4*)(d + t * 4) = u;
}

// ======= m97-style GEMM: 128x128 tile, BK=64, 4 waves, single 32KB buffer ===
// (proven round-10 kernel; used for V^T, PV, Wo)
// EPI 0: bf16   2: bf16 + aux residual (batched f32)   3: f32, +bias[col], relu
// MSK 0: none   2 (PV): if tileM >= l[bz], emit y = bf16(x) and skip
template <int EPI, int MSK>
__global__ __launch_bounds__(256, 4) void gemm97(
    const u16* __restrict__ A, const u16* __restrict__ B, void* __restrict__ Cv,
    int K, int lda, int ldb, int ldc,
    long sA, long sB, long sC,
    const float* __restrict__ aux, long sAux,
    const int* __restrict__ lptr) {
  __shared__ __align__(16) u16 As[128 * 64];
  __shared__ __align__(16) u16 Bs[128 * 64];
  const int bz = blockIdx.z;
  const u16* Ab = A + (size_t)bz * sA;
  const u16* Bb = B + (size_t)bz * sB;

  const int nb = gridDim.x * gridDim.y;
  int bid = blockIdx.y * gridDim.x + blockIdx.x;
  bid = (bid & 7) * (nb >> 3) + (bid >> 3);
  const int gx = gridDim.x;
  const int tileN = (bid % gx) * 128;
  const int tileM = (bid / gx) * 128;

  const int t = threadIdx.x;

  if constexpr (MSK == 2) {
    if (tileM >= lptr[bz]) {                  // P rows zero -> y = x
      const float* xb = aux + (size_t)bz * sAux;
      u16* yo = (u16*)Cv + (size_t)bz * sC;
      for (int e = t; e < (128 * 128) / 8; e += 256) {
        const int row = tileM + (e >> 4);
        const int col = tileN + ((e & 15) << 3);
        const float4 v0 = *(const float4*)(xb + (size_t)row * ldc + col);
        const float4 v1 = *(const float4*)(xb + (size_t)row * ldc + col + 4);
        ushort4 o0; o0.x = f2bf(v0.x); o0.y = f2bf(v0.y); o0.z = f2bf(v0.z); o0.w = f2bf(v0.w);
        ushort4 o1; o1.x = f2bf(v1.x); o1.y = f2bf(v1.y); o1.z = f2bf(v1.z); o1.w = f2bf(v1.w);
        *(ushort4*)(yo + (size_t)row * ldc + col) = o0;
        *(ushort4*)(yo + (size_t)row * ldc + col + 4) = o1;
      }
      return;
    }
  }

  const int lane = t & 63;
  const int wid = t >> 6;
  const int wm = wid >> 1, wn = wid & 1;      // 2 x 2 waves

  const int r0s = t >> 3;
  const int sch = ((t & 7) ^ (r0s & 7)) * 8;

  const int frow = lane & 15, kg = lane >> 4, f7 = lane & 7;

  f32x4 acc[4][4] = {};

  for (int k0 = 0; k0 < K; k0 += 64) {
    if (k0) __syncthreads();
#pragma unroll
    for (int i = 0; i < 4; ++i) {
      const int e = i * 256 + t;
      const int row = i * 32 + r0s;
      gload_lds16(Ab + (size_t)(tileM + row) * lda + k0 + sch, &As[e * 8]);
      gload_lds16(Bb + (size_t)(tileN + row) * ldb + k0 + sch, &Bs[e * 8]);
    }
    __syncthreads();
#pragma unroll
    for (int h = 0; h < 2; ++h) {
      const int cs = (((h * 4 + kg) ^ f7)) * 8;
      bf16x8 af[4], bf[4];
#pragma unroll
      for (int i = 0; i < 4; ++i)
        af[i] = *(const bf16x8*)&As[(wm * 64 + i * 16 + frow) * 64 + cs];
#pragma unroll
      for (int j = 0; j < 4; ++j)
        bf[j] = *(const bf16x8*)&Bs[(wn * 64 + j * 16 + frow) * 64 + cs];
#pragma unroll
      for (int i = 0; i < 4; ++i)
#pragma unroll
        for (int j = 0; j < 4; ++j)
          acc[i][j] = __builtin_amdgcn_mfma_f32_16x16x32_bf16(af[i], bf[j], acc[i][j], 0, 0, 0);
    }
  }

  const int r0 = tileM + wm * 64 + (kg << 2);
  const int c0 = tileN + wn * 64 + frow;
#pragma unroll
  for (int i = 0; i < 4; ++i)
#pragma unroll
    for (int j = 0; j < 4; ++j)
#pragma unroll
      for (int r = 0; r < 4; ++r) {
        const int row = r0 + i * 16 + r, col = c0 + j * 16;
        const size_t idx = (size_t)row * ldc + col;
        float v = acc[i][j][r];
        if constexpr (EPI == 0) {
          ((u16*)Cv + (size_t)bz * sC)[idx] = f2bf(v);
        } else if constexpr (EPI == 2) {
          v += (aux + (size_t)bz * sAux)[idx];
          ((u16*)Cv + (size_t)bz * sC)[idx] = f2bf(v);
        } else {
          v += aux[col];
          ((float*)Cv + (size_t)bz * sC)[idx] = fmaxf(v, 0.f);
        }
      }
}

// ==== wide GEMM, 8 waves: BM=128 x BN=256, wave grid 2Mx4N, wave tile 64x64 =
// acc[4][4], BK=64, single 48KB LDS buffer, 512 threads, 2 blocks/CU.
// Masked dispatches leave ~1 live block/CU; 8 waves/block restores 2
// waves/SIMD of TLP on live CUs (vs 1 with 4-wave blocks).
// EPI 0: bf16   1: fp16*scale + fused per-column masked (max,sumexp) partials
// MSK 1: skip tile if tileM >= l[bz]
// MSK 3 (QK): skip Q-half tiles (tileN < DIM) whose rows are all >= l[batch]
template <int EPI, int MSK>
__global__ __launch_bounds__(512, 4) void gemm_bw(
    const u16* __restrict__ A, const u16* __restrict__ B, void* __restrict__ Cv,
    int K, int lda, int ldb, int ldc,
    long sA, long sB, long sC, float scale,
    const int* __restrict__ lptr, float* __restrict__ mpQ, float* __restrict__ zpQ) {
  __shared__ __align__(16) u16 As[128 * 64];   // 16 KB
  __shared__ __align__(16) u16 Bs[256 * 64];   // 32 KB
  const int bz = blockIdx.z;
  const u16* Ab = A + (size_t)bz * sA;
  const u16* Bb = B + (size_t)bz * sB;

  const int nb = gridDim.x * gridDim.y;
  int bid = blockIdx.y * gridDim.x + blockIdx.x;
  bid = (bid & 7) * (nb >> 3) + (bid >> 3);
  const int gx = gridDim.x;
  const int tileN = (bid % gx) * 256;
  const int tileM = (bid / gx) * 128;

  const int t = threadIdx.x;

  if constexpr (MSK == 1) {
    if (tileM >= lptr[bz]) return;
  }
  if constexpr (MSK == 3) {
    if (((tileM & (T_SEQ - 1)) >= lptr[tileM >> 11]) && tileN < DIM) return;
  }

  const int lane = t & 63;
  const int wid = t >> 6;                     // 0..7
  const int wm = wid >> 2, wn = wid & 3;      // 2M x 4N waves

  // staging: unit e; A: e = i*512 + t (i<2), row = i*64 + (t>>3), slot = t&7
  //          B: e = i*512 + t (i<4), row = i*64 + (t>>3)
  const int r0s = t >> 3;                     // 0..63
  const int sch = ((t & 7) ^ (r0s & 7)) * 8;  // row&7 invariant across i (64%8==0)

  const int frow = lane & 15, kg = lane >> 4, f7 = lane & 7;

  f32x4 acc[4][4] = {};

  for (int k0 = 0; k0 < K; k0 += 64) {
    if (k0) __syncthreads();
#pragma unroll
    for (int i = 0; i < 2; ++i) {
      const int row = i * 64 + r0s;
      gload_lds16(Ab + (size_t)(tileM + row) * lda + k0 + sch, &As[(i * 512 + t) * 8]);
    }
#pragma unroll
    for (int i = 0; i < 4; ++i) {
      const int row = i * 64 + r0s;
      gload_lds16(Bb + (size_t)(tileN + row) * ldb + k0 + sch, &Bs[(i * 512 + t) * 8]);
    }
    __syncthreads();
#pragma unroll
    for (int h = 0; h < 2; ++h) {
      const int cs = (((h * 4 + kg) ^ f7)) * 8;
      bf16x8 af[4], bf[4];
#pragma unroll
      for (int i = 0; i < 4; ++i)
        af[i] = *(const bf16x8*)&As[(wm * 64 + i * 16 + frow) * 64 + cs];
#pragma unroll
      for (int j = 0; j < 4; ++j)
        bf[j] = *(const bf16x8*)&Bs[(wn * 64 + j * 16 + frow) * 64 + cs];
#pragma unroll
      for (int i = 0; i < 4; ++i)
#pragma unroll
        for (int j = 0; j < 4; ++j)
          acc[i][j] = __builtin_amdgcn_mfma_f32_16x16x32_bf16(af[i], bf[j], acc[i][j], 0, 0, 0);
    }
  }

  const int r0 = tileM + wm * 64 + (kg << 2);
  const int c0 = tileN + wn * 64 + frow;
#pragma unroll
  for (int i = 0; i < 4; ++i)
#pragma unroll
    for (int j = 0; j < 4; ++j)
#pragma unroll
      for (int r = 0; r < 4; ++r) {
        const int row = r0 + i * 16 + r, col = c0 + j * 16;
        const size_t idx = (size_t)row * ldc + col;
        const float v = acc[i][j][r];
        if constexpr (EPI == 0) {
          ((u16*)Cv + (size_t)bz * sC)[idx] = f2bf(v);
        } else {
          ((__half*)Cv + (size_t)bz * sC)[idx] = __float2half(v * scale);
        }
      }

  // ---- EPI 1: fused per-column (over rows i, masked i<L) max & sumexp ------
  if constexpr (EPI == 1) {
    const int L = lptr[bz];
    __shared__ float2 red[2][4][4][16];   // [wm][wn][j][frow]
    float Ms[4], Zs[4];
#pragma unroll
    for (int j = 0; j < 4; ++j) {
      float mj = -3e38f;
#pragma unroll
      for (int i = 0; i < 4; ++i)
#pragma unroll
        for (int r = 0; r < 4; ++r) {
          const int row = r0 + i * 16 + r;
          if (row < L) mj = fmaxf(mj, acc[i][j][r] * scale);
        }
      mj = fmaxf(mj, __shfl_xor(mj, 16, 64));
      mj = fmaxf(mj, __shfl_xor(mj, 32, 64));
      float zj = 0.f;
#pragma unroll
      for (int i = 0; i < 4; ++i)
#pragma unroll
        for (int r = 0; r < 4; ++r) {
          const int row = r0 + i * 16 + r;
          if (row < L) zj += __expf(acc[i][j][r] * scale - mj);
        }
      zj += __shfl_xor(zj, 16, 64);
      zj += __shfl_xor(zj, 32, 64);
      Ms[j] = mj; Zs[j] = zj;
    }
    if (lane < 16) {
#pragma unroll
      for (int j = 0; j < 4; ++j) red[wm][wn][j][frow] = make_float2(Ms[j], Zs[j]);
    }
    __syncthreads();
    if (wm == 0 && lane < 16) {
#pragma unroll
      for (int j = 0; j < 4; ++j) {
        const float2 a = red[0][wn][j][frow];
        const float2 b = red[1][wn][j][frow];
        const float M = fmaxf(a.x, b.x);
        const float Z = a.y * __expf(a.x - M) + b.y * __expf(b.x - M);
        const int col = tileN + wn * 64 + j * 16 + frow;
        const size_t o = ((size_t)(tileM >> 7) * NB + bz) * T_SEQ + col;
        mpQ[o] = M; zpQ[o] = Z;
      }
    }
  }
}

// ------- combine live chunk partials per column -> m, 1/Z -------------------
__global__ __launch_bounds__(256) void colreduce_comb(const float* __restrict__ mp,
                                                      const float* __restrict__ zp,
                                                      const int* __restrict__ l,
                                                      float* __restrict__ m,
                                                      float* __restrict__ rz) {
  const int b = blockIdx.y;
  const int j = blockIdx.x * 256 + threadIdx.x;
  const int L = l[b];
  float M = -3e38f, Z = 0.f;
  for (int c = 0; c < NCH && (c << 7) < L; ++c) {
    const size_t o = ((size_t)c * NB + b) * T_SEQ + j;
    const float mc = mp[o], zc = zp[o];
    const float nm = fmaxf(M, mc);
    Z = Z * __expf(M - nm) + zc * __expf(mc - nm);
    M = nm;
  }
  m[b * T_SEQ + j] = M;
  rz[b * T_SEQ + j] = 1.f / Z;
}

// ---------------- P = exp(S - m) / Z  (bf16, row-masked) -------------------
__global__ __launch_bounds__(256) void pbuild(const __half* __restrict__ S,
                                              const int* __restrict__ l,
                                              const float* __restrict__ m,
                                              const float* __restrict__ rz,
                                              u16* __restrict__ P) {
  const int b = blockIdx.x >> 11;
  const int i = blockIdx.x & (T_SEQ - 1);
  const int L = l[b];
  if (i >= ((L + 127) & ~127)) return;
  const int j0 = threadIdx.x * 8;
  const size_t off = ((size_t)blockIdx.x << 11) + j0;
  ushort4 o0, o1;
  if (i < L) {
    const __half* sp = S + off;
    const float* mp = m + b * T_SEQ + j0;
    const float* zp = rz + b * T_SEQ + j0;
    u16 tmp[8];
#pragma unroll
    for (int tt = 0; tt < 8; ++tt)
      tmp[tt] = f2bf(__expf(__half2float(sp[tt]) - mp[tt]) * zp[tt]);
    o0 = make_ushort4(tmp[0], tmp[1], tmp[2], tmp[3]);
    o1 = make_ushort4(tmp[4], tmp[5], tmp[6], tmp[7]);
  } else {
    o0 = make_ushort4(0, 0, 0, 0);
    o1 = make_ushort4(0, 0, 0, 0);
  }
  *(ushort4*)(P + off) = o0;
  *(ushort4*)(P + off + 4) = o1;
}

// ---------------------------------------------------------------------------
extern "C" void kernel_launch(void* const* d_in, const int* in_sizes, int n_in,
                              void* d_out, int out_size, void* d_ws, size_t ws_size,
                              hipStream_t stream) {
  (void)in_sizes; (void)n_in; (void)out_size; (void)ws_size;
  const float* x     = (const float*)d_in[0];
  const int*   l     = (const int*)d_in[1];
  const float* Wq    = (const float*)d_in[2];
  const float* Wk    = (const float*)d_in[3];
  const float* Wv    = (const float*)d_in[4];
  const float* Wo    = (const float*)d_in[5];
  const float* bo    = (const float*)d_in[6];
  const float* gamma = (const float*)d_in[7];
  const float* beta  = (const float*)d_in[8];

  char* ws = (char*)d_ws;
  const size_t MiB = 1024 * 1024;
  u16* xn   = (u16*)(ws);             // 16 MiB x_norm; later reused as y
  u16* wqkb = (u16*)(ws + 16 * MiB);  // 4 MiB: Wq rows then Wk rows (concat)
  u16* wvb  = (u16*)(ws + 20 * MiB);  // 2 MiB; later reused for softmax partials
  u16* wob  = (u16*)(ws + 22 * MiB);  // 2 MiB
  u16* QKb  = (u16*)(ws + 24 * MiB);  // 32 MiB: [8192][2048] Q|K; reused as P
  u16* Vt   = (u16*)(ws + 56 * MiB);  // 16 MiB: [1024][8192] V^T (all batches)
  float* mpart = (float*)(ws + 20 * MiB);                // 512 KiB (over dead wvb)
  float* zpart = (float*)(ws + 20 * MiB + 512 * 1024);   // 512 KiB
  float* mb  = (float*)(ws + 72 * MiB);
  float* rzb = (float*)(ws + 72 * MiB + 32 * 1024);
  u16* Pb = QKb;                      // P overwrites dead Q|K
  u16* yb = xn;
  __half* S = (__half*)d_out;         // d_out doubles as the 32 MiB score scratch
  float* outp = (float*)d_out;

  const long TD = (long)T_SEQ * DIM, TT = (long)T_SEQ * T_SEQ;
  const long TQK = (long)T_SEQ * 2048;

  ln_kernel<<<NB * T_SEQ, 256, 0, stream>>>(x, gamma, beta, xn);
  wcvt4<<<4096, 256, 0, stream>>>(Wq, Wk, Wv, Wo, wqkb, wvb, wob);

  // Q|K = xn @ [Wq;Wk]^T  [8192,2048]  grid 8x64 = 512 (dead Q-tiles skip)
  gemm_bw<0, 3><<<dim3(8, 64, 1), 512, 0, stream>>>(
      xn, wqkb, QKb, DIM, DIM, DIM, 2048, 0, 0, 0, 0.f,
      l, nullptr, nullptr);
  // V^T = Wv_bf @ xn^T   [1024, 8192]   grid 64x8 = 512
  gemm97<0, 0><<<dim3(64, 8, 1), 256, 0, stream>>>(
      wvb, xn, Vt, DIM, DIM, DIM, 8192, 0, 0, 0, nullptr, 0, nullptr);
  // S[b] = (Q_b @ K_b^T)*scale -> fp16, + fused per-column partial (m,z)
  // grid 8x16x4 = 512 (tiles with all rows masked skip; slots refill)
  gemm_bw<1, 1><<<dim3(8, 16, NB), 512, 0, stream>>>(
      QKb, QKb + 1024, S, DIM, 2048, 2048, T_SEQ, TQK, TQK, TT, 0.03125f,
      l, mpart, zpart);
  // combine live chunk partials -> m, 1/Z
  colreduce_comb<<<dim3(T_SEQ / 256, NB), 256, 0, stream>>>(mpart, zpart, l, mb, rzb);
  // P = exp(S-m)*rz (bf16), zero straddle band, skip fully-dead rows
  pbuild<<<NB * T_SEQ, 256, 0, stream>>>(S, l, mb, rzb, Pb);
  // y[b] = x_b + P_b @ Vt_b^T  [2048,1024] bf16  grid 8x16x4 = 512
  gemm97<2, 2><<<dim3(8, 16, NB), 256, 0, stream>>>(
      Pb, Vt, yb, T_SEQ, T_SEQ, 8192, DIM, TT, 2048, TD, x, TD, l);
  // out = relu(y @ Wo^T + bo)  f32   grid 8x64 = 512
  gemm97<3, 0><<<dim3(8, 64, 1), 256, 0, stream>>>(
      yb, wob, outp, DIM, DIM, DIM, DIM, 0, 0, 0, bo, 0, nullptr);
}